// Round 1
// baseline (811.166 us; speedup 1.0000x reference)
//
#include <hip/hip_runtime.h>

constexpr float NEG_SLOPE = 0.2f;
constexpr float EPS = 1e-16f;

// ---------------- CSR build ----------------

__global__ void count_k(const int* __restrict__ dst, int* __restrict__ cnt, int E) {
    int i = blockIdx.x * blockDim.x + threadIdx.x;
    if (i < E) atomicAdd(&cnt[dst[i]], 1);
}

// block-level exclusive scan (256/block), emits block sums
__global__ void scan1_k(const int* __restrict__ in, int* __restrict__ out,
                        int* __restrict__ bsum, int n) {
    __shared__ int s[256];
    int tid = threadIdx.x;
    int i = blockIdx.x * 256 + tid;
    int v = (i < n) ? in[i] : 0;
    s[tid] = v;
    __syncthreads();
    #pragma unroll
    for (int off = 1; off < 256; off <<= 1) {
        int t = (tid >= off) ? s[tid - off] : 0;
        __syncthreads();
        s[tid] += t;
        __syncthreads();
    }
    if (i < n) out[i] = s[tid] - v;           // exclusive
    if (tid == 255) bsum[blockIdx.x] = s[255]; // block total
}

// single-block exclusive scan of block sums (nb <= 1024)
__global__ void scan2_k(int* __restrict__ bsum, int nb) {
    __shared__ int s[1024];
    int tid = threadIdx.x;
    int v = (tid < nb) ? bsum[tid] : 0;
    s[tid] = v;
    __syncthreads();
    #pragma unroll
    for (int off = 1; off < 1024; off <<= 1) {
        int t = (tid >= off) ? s[tid - off] : 0;
        __syncthreads();
        s[tid] += t;
        __syncthreads();
    }
    if (tid < nb) bsum[tid] = s[tid] - v;      // exclusive
}

__global__ void scan3_k(int* __restrict__ rowptr, const int* __restrict__ bsum,
                        int n, int E) {
    int i = blockIdx.x * 256 + threadIdx.x;
    if (i < n) rowptr[i] += bsum[blockIdx.x];
    if (i == 0) rowptr[n] = E;
}

__global__ void fill_k(const int* __restrict__ src, const int* __restrict__ dst,
                       const int* __restrict__ rowptr, int* __restrict__ fill,
                       int* __restrict__ ssrc, int* __restrict__ seid, int E) {
    int i = blockIdx.x * blockDim.x + threadIdx.x;
    if (i < E) {
        int d = dst[i];
        int pos = rowptr[d] + atomicAdd(&fill[d], 1);
        ssrc[pos] = src[i];
        seid[pos] = i;
    }
}

// mean incoming edge_attr per node (0 if no incoming edges)
__global__ void mean_k(const float* __restrict__ ea, const int* __restrict__ seid,
                       const int* __restrict__ rowptr, float* __restrict__ mattr, int N) {
    int t = blockIdx.x * blockDim.x + threadIdx.x;
    if (t >= N * 16) return;
    int v = t >> 4, f = t & 15;
    int s = rowptr[v], e = rowptr[v + 1];
    float sum = 0.f;
    for (int k = s; k < e; k++) sum += ea[(size_t)seid[k] * 16 + f];
    int c = e - s;
    mattr[t] = sum / (float)(c > 1 ? c : 1);
}

// ---------------- node transforms: xl = x@Wl+bl, xr = x@Wr+br ----------------

__global__ __launch_bounds__(256) void xfrm_k(
        const float* __restrict__ x,
        const float* __restrict__ Wl, const float* __restrict__ bl,
        const float* __restrict__ Wr, const float* __restrict__ br,
        float* __restrict__ xl, float* __restrict__ xr, int N) {
    __shared__ float sWl[64 * 64];
    __shared__ float sWr[64 * 64];
    for (int i = threadIdx.x; i < 64 * 64; i += 256) {
        sWl[i] = Wl[i];
        sWr[i] = Wr[i];
    }
    __syncthreads();
    int v = blockIdx.x * 4 + (threadIdx.x >> 6);
    int h = threadIdx.x & 63;
    if (v >= N) return;
    const float4* xrow = reinterpret_cast<const float4*>(x + (size_t)v * 64);
    float al = bl[h], ar = br[h];
    #pragma unroll
    for (int d4 = 0; d4 < 16; d4++) {
        float4 xv = xrow[d4];   // broadcast across the wave
        int d = d4 * 4;
        al = fmaf(xv.x, sWl[(d + 0) * 64 + h], al);
        al = fmaf(xv.y, sWl[(d + 1) * 64 + h], al);
        al = fmaf(xv.z, sWl[(d + 2) * 64 + h], al);
        al = fmaf(xv.w, sWl[(d + 3) * 64 + h], al);
        ar = fmaf(xv.x, sWr[(d + 0) * 64 + h], ar);
        ar = fmaf(xv.y, sWr[(d + 1) * 64 + h], ar);
        ar = fmaf(xv.z, sWr[(d + 2) * 64 + h], ar);
        ar = fmaf(xv.w, sWr[(d + 3) * 64 + h], ar);
    }
    xl[(size_t)v * 64 + h] = al;
    xr[(size_t)v * 64 + h] = ar;
}

// ---------------- per-node GATv2 aggregation (flash-style online softmax) ----------------
// one wave per node; lane = feature. MODE 0: write h1 = relu(out). MODE 1: fuse
// h2 = relu(out), JK-cat readout -> d_out[v] scalar.

template <int MODE>
__global__ __launch_bounds__(256) void node_k(
        const float* __restrict__ xl, const float* __restrict__ xr,
        const float* __restrict__ ea, const float* __restrict__ mattr,
        const int* __restrict__ ssrc, const int* __restrict__ seid,
        const int* __restrict__ rowptr,
        const float* __restrict__ We, const float* __restrict__ att,
        const float* __restrict__ bc,
        float* __restrict__ hout,
        const float* __restrict__ h1, const float* __restrict__ Wout,
        const float* __restrict__ bout, float* __restrict__ out, int N) {
    int lane = threadIdx.x & 63;
    int v = blockIdx.x * 4 + (threadIdx.x >> 6);
    if (v >= N) return;

    float wec[16];
    #pragma unroll
    for (int d = 0; d < 16; d++) wec[d] = We[d * 64 + lane];  // column of We
    float att_h = att[lane];
    float xr_h = xr[(size_t)v * 64 + lane];

    int s = rowptr[v], e = rowptr[v + 1];
    float m = -1e30f, denom = 0.f, acc = 0.f;

    for (int k = s; k <= e; k++) {  // k == e is the self-loop
        int srcn;
        const float* ear;
        if (k < e) {
            srcn = ssrc[k];
            ear = ea + (size_t)seid[k] * 16;
        } else {
            srcn = v;
            ear = mattr + (size_t)v * 16;
        }
        const float4* eq = reinterpret_cast<const float4*>(ear);
        float4 q0 = eq[0], q1 = eq[1], q2 = eq[2], q3 = eq[3];
        float ee = q0.x * wec[0];
        ee = fmaf(q0.y, wec[1], ee);
        ee = fmaf(q0.z, wec[2], ee);
        ee = fmaf(q0.w, wec[3], ee);
        ee = fmaf(q1.x, wec[4], ee);
        ee = fmaf(q1.y, wec[5], ee);
        ee = fmaf(q1.z, wec[6], ee);
        ee = fmaf(q1.w, wec[7], ee);
        ee = fmaf(q2.x, wec[8], ee);
        ee = fmaf(q2.y, wec[9], ee);
        ee = fmaf(q2.z, wec[10], ee);
        ee = fmaf(q2.w, wec[11], ee);
        ee = fmaf(q3.x, wec[12], ee);
        ee = fmaf(q3.y, wec[13], ee);
        ee = fmaf(q3.z, wec[14], ee);
        ee = fmaf(q3.w, wec[15], ee);

        float xls = xl[(size_t)srcn * 64 + lane];
        float mv = xls + xr_h + ee;
        mv = (mv > 0.f) ? mv : NEG_SLOPE * mv;
        float p = att_h * mv;
        #pragma unroll
        for (int off = 32; off; off >>= 1) p += __shfl_xor(p, off);
        // p now = e_k on all lanes
        float mnew = fmaxf(m, p);
        float sc = __expf(m - mnew);
        float w = __expf(p - mnew);
        denom = denom * sc + w;
        acc = acc * sc + w * xls;
        m = mnew;
    }

    float res = acc / (denom + EPS) + bc[lane];
    res = fmaxf(res, 0.f);  // relu on layer output

    if (MODE == 0) {
        hout[(size_t)v * 64 + lane] = res;
    } else {
        float part = h1[(size_t)v * 64 + lane] * Wout[lane] + res * Wout[64 + lane];
        #pragma unroll
        for (int off = 32; off; off >>= 1) part += __shfl_xor(part, off);
        if (lane == 0) out[v] = part + bout[0];
    }
}

// ---------------- launch ----------------

extern "C" void kernel_launch(void* const* d_in, const int* in_sizes, int n_in,
                              void* d_out, int out_size, void* d_ws, size_t ws_size,
                              hipStream_t stream) {
    const float* x     = (const float*)d_in[0];
    const int*   eidx  = (const int*)d_in[1];
    const float* eattr = (const float*)d_in[2];
    const float* Wl1 = (const float*)d_in[4];
    const float* bl1 = (const float*)d_in[5];
    const float* Wr1 = (const float*)d_in[6];
    const float* br1 = (const float*)d_in[7];
    const float* We1 = (const float*)d_in[8];
    const float* att1 = (const float*)d_in[9];
    const float* bc1 = (const float*)d_in[10];
    const float* Wl2 = (const float*)d_in[11];
    const float* bl2 = (const float*)d_in[12];
    const float* Wr2 = (const float*)d_in[13];
    const float* br2 = (const float*)d_in[14];
    const float* We2 = (const float*)d_in[15];
    const float* att2 = (const float*)d_in[16];
    const float* bc2 = (const float*)d_in[17];
    const float* Wout = (const float*)d_in[18];
    const float* bout = (const float*)d_in[19];

    int N = in_sizes[0] / 64;
    int E = in_sizes[1] / 2;
    const int* srcA = eidx;
    const int* dstA = eidx + E;

    // workspace carve (256B aligned)
    char* w = (char*)d_ws;
    auto alloc = [&](size_t bytes) {
        char* p = w;
        w += (bytes + 255) & ~size_t(255);
        return p;
    };
    int*   cnt    = (int*)alloc((size_t)N * 4);
    int*   fill   = (int*)alloc((size_t)N * 4);
    int*   rowptr = (int*)alloc((size_t)(N + 1) * 4);
    int*   bsum   = (int*)alloc(1024 * 4);
    int*   ssrc   = (int*)alloc((size_t)E * 4);
    int*   seid   = (int*)alloc((size_t)E * 4);
    float* mattr  = (float*)alloc((size_t)N * 16 * 4);
    float* xl     = (float*)alloc((size_t)N * 64 * 4);
    float* xr     = (float*)alloc((size_t)N * 64 * 4);
    float* h1     = (float*)alloc((size_t)N * 64 * 4);

    hipMemsetAsync(cnt, 0, (size_t)N * 4, stream);
    hipMemsetAsync(fill, 0, (size_t)N * 4, stream);

    int NB = (N + 255) / 256;
    count_k<<<(E + 255) / 256, 256, 0, stream>>>(dstA, cnt, E);
    scan1_k<<<NB, 256, 0, stream>>>(cnt, rowptr, bsum, N);
    scan2_k<<<1, 1024, 0, stream>>>(bsum, NB);
    scan3_k<<<NB, 256, 0, stream>>>(rowptr, bsum, N, E);
    fill_k<<<(E + 255) / 256, 256, 0, stream>>>(srcA, dstA, rowptr, fill, ssrc, seid, E);
    mean_k<<<(N * 16 + 255) / 256, 256, 0, stream>>>(eattr, seid, rowptr, mattr, N);

    int nodeBlocks = (N + 3) / 4;
    // layer 1
    xfrm_k<<<nodeBlocks, 256, 0, stream>>>(x, Wl1, bl1, Wr1, br1, xl, xr, N);
    node_k<0><<<nodeBlocks, 256, 0, stream>>>(xl, xr, eattr, mattr, ssrc, seid, rowptr,
                                              We1, att1, bc1, h1,
                                              nullptr, nullptr, nullptr, nullptr, N);
    // layer 2 (+ fused JK-cat readout)
    xfrm_k<<<nodeBlocks, 256, 0, stream>>>(h1, Wl2, bl2, Wr2, br2, xl, xr, N);
    node_k<1><<<nodeBlocks, 256, 0, stream>>>(xl, xr, eattr, mattr, ssrc, seid, rowptr,
                                              We2, att2, bc2, nullptr,
                                              h1, Wout, bout, (float*)d_out, N);
}